// Round 1
// baseline (2916.365 us; speedup 1.0000x reference)
//
#include <hip/hip_runtime.h>

#define TT 8192      // tokens
#define HD 2048      // hidden
#define FFN 5632
#define NE 8

#define BM 128
#define BN 128
#define BK 32
#define LDK 40       // padded fp16 elems per LDS row (80B stride)

typedef float f32x4 __attribute__((ext_vector_type(4)));
typedef _Float16 f16x4 __attribute__((ext_vector_type(4)));
typedef _Float16 f16x8 __attribute__((ext_vector_type(8)));

// workspace layout (bytes)
#define OFF_WR    0u          // 16384 f32 = 65536
#define OFF_CNT   65536u      // 8 int (zeroed per launch)
#define OFF_LISTS 66048u      // 8*8192 int = 262144
#define OFF_TOKW  328192u     // 16384 f32 = 65536
#define OFF_ACT   1048576u    // 16384*5632 f16 = 184549376

__device__ __forceinline__ f16x4 cvt4(f32x4 v) {
  f16x4 r;
  r[0] = (_Float16)v[0]; r[1] = (_Float16)v[1];
  r[2] = (_Float16)v[2]; r[3] = (_Float16)v[3];
  return r;
}

__global__ __launch_bounds__(256) void k_prep(const float* __restrict__ wg,
                                              const float* __restrict__ wge,
                                              float* __restrict__ wr) {
  int i = blockIdx.x * 256 + threadIdx.x;
  if (i < HD * NE) wr[i] = 0.5f * (wge[i] + wg[i]);
}

__global__ __launch_bounds__(256) void k_router(const float* __restrict__ x,
                                                const float* __restrict__ wr,
                                                float* __restrict__ logits,
                                                float* __restrict__ tokw,
                                                int* __restrict__ lists,
                                                int* __restrict__ cnt) {
  const int t = blockIdx.x, tid = threadIdx.x;
  const float* xr = x + (size_t)t * HD;
  float acc[NE];
#pragma unroll
  for (int e = 0; e < NE; ++e) acc[e] = 0.f;
  for (int h = tid; h < HD; h += 256) {
    float xv = xr[h];
    const float* w = wr + h * NE;
#pragma unroll
    for (int e = 0; e < NE; ++e) acc[e] = fmaf(xv, w[e], acc[e]);
  }
#pragma unroll
  for (int e = 0; e < NE; ++e)
#pragma unroll
    for (int off = 32; off; off >>= 1)
      acc[e] += __shfl_xor(acc[e], off, 64);
  __shared__ float red[4][NE];
  int wv = tid >> 6;
  if ((tid & 63) == 0)
    for (int e = 0; e < NE; ++e) red[wv][e] = acc[e];
  __syncthreads();
  if (tid == 0) {
    float l[NE];
#pragma unroll
    for (int e = 0; e < NE; ++e) l[e] = red[0][e] + red[1][e] + red[2][e] + red[3][e];
#pragma unroll
    for (int e = 0; e < NE; ++e) logits[(size_t)t * NE + e] = l[e];
    int i0 = 0;
    for (int e = 1; e < NE; ++e) if (l[e] > l[i0]) i0 = e;
    int i1 = -1;
    for (int e = 0; e < NE; ++e) if (e != i0 && (i1 < 0 || l[e] > l[i1])) i1 = e;
    // softmax over top-2 == top_vals/top_vals.sum (softmax ratio)
    float p1 = __expf(l[i1] - l[i0]);
    float s = 1.f + p1;
    tokw[t * 2]     = 1.f / s;
    tokw[t * 2 + 1] = p1 / s;
    int q0 = atomicAdd(&cnt[i0], 1);
    lists[i0 * TT + q0] = t * 2;
    int q1 = atomicAdd(&cnt[i1], 1);
    lists[i1 * TT + q1] = t * 2 + 1;
  }
}

// Stage A: for expert e, rows = routed token list, compute
// act = silu(x@fc1_1[e]^T) * (x@fc1_2[e]^T) -> fp16, scattered by pair id.
__global__ __launch_bounds__(512) void k_ffn1(const float* __restrict__ x,
                                              const float* __restrict__ fc11,
                                              const float* __restrict__ fc12,
                                              const int* __restrict__ lists,
                                              const int* __restrict__ cnt,
                                              _Float16* __restrict__ act) {
  const int e = blockIdx.z, rt = blockIdx.y, ct = blockIdx.x;
  const int count = cnt[e];
  if (rt * BM >= count) return;
  const int tid = threadIdx.x;

  __shared__ _Float16 As[2][BM][LDK];
  __shared__ _Float16 B1s[2][BN][LDK];
  __shared__ _Float16 B2s[2][BN][LDK];
  __shared__ int row_pair[BM];

  if (tid < BM) {
    int rg = rt * BM + tid;
    row_pair[tid] = (rg < count) ? lists[e * TT + rg] : -1;
  }
  __syncthreads();

  const float* pa[2]; const float* pb1[2]; const float* pb2[2];
  int soff[2];
#pragma unroll
  for (int i = 0; i < 2; ++i) {
    int idx = tid + i * 512;
    int r = idx >> 3, c4 = (idx & 7) * 4;
    soff[i] = r * LDK + c4;
    int pr = row_pair[r];
    pa[i] = (pr >= 0) ? (x + (size_t)(pr >> 1) * HD + c4) : nullptr;
    size_t br = (size_t)e * FFN + (size_t)ct * BN + r;
    pb1[i] = fc11 + br * HD + c4;
    pb2[i] = fc12 + br * HD + c4;
  }

  const f32x4 zero4 = {0.f, 0.f, 0.f, 0.f};
  f32x4 la[2], lb1[2], lb2[2];
  auto load_tile = [&](int k0) {
#pragma unroll
    for (int i = 0; i < 2; ++i) {
      la[i]  = pa[i] ? *(const f32x4*)(pa[i] + k0) : zero4;
      lb1[i] = *(const f32x4*)(pb1[i] + k0);
      lb2[i] = *(const f32x4*)(pb2[i] + k0);
    }
  };
  auto write_tile = [&](int buf) {
#pragma unroll
    for (int i = 0; i < 2; ++i) {
      *(f16x4*)&As[buf][0][soff[i]]  = cvt4(la[i]);
      *(f16x4*)&B1s[buf][0][soff[i]] = cvt4(lb1[i]);
      *(f16x4*)&B2s[buf][0][soff[i]] = cvt4(lb2[i]);
    }
  };

  f32x4 acc1[2][4], acc2[2][4];
#pragma unroll
  for (int m = 0; m < 2; ++m)
#pragma unroll
    for (int n = 0; n < 4; ++n) { acc1[m][n] = zero4; acc2[m][n] = zero4; }

  const int lane = tid & 63;
  const int wv = tid >> 6;
  const int wrow = (wv >> 1) * 32;  // 4 row-groups of 32
  const int wcol = (wv & 1) * 64;   // 2 col-groups of 64
  const int fr = lane & 15;
  const int kg = lane >> 4;

  load_tile(0);
  write_tile(0);
  __syncthreads();

  const int NS = HD / BK;  // 64
  for (int ks = 0; ks < NS; ++ks) {
    int buf = ks & 1;
    if (ks + 1 < NS) load_tile((ks + 1) * BK);
    f16x8 a[2], b1[4], b2[4];
#pragma unroll
    for (int m = 0; m < 2; ++m)
      a[m] = *(const f16x8*)&As[buf][wrow + m * 16 + fr][kg * 8];
#pragma unroll
    for (int n = 0; n < 4; ++n) {
      b1[n] = *(const f16x8*)&B1s[buf][wcol + n * 16 + fr][kg * 8];
      b2[n] = *(const f16x8*)&B2s[buf][wcol + n * 16 + fr][kg * 8];
    }
#pragma unroll
    for (int m = 0; m < 2; ++m)
#pragma unroll
      for (int n = 0; n < 4; ++n) {
        acc1[m][n] = __builtin_amdgcn_mfma_f32_16x16x32_f16(a[m], b1[n], acc1[m][n], 0, 0, 0);
        acc2[m][n] = __builtin_amdgcn_mfma_f32_16x16x32_f16(a[m], b2[n], acc2[m][n], 0, 0, 0);
      }
    if (ks + 1 < NS) write_tile(buf ^ 1);
    __syncthreads();
  }

  // epilogue: act = silu(h1) * h2, store fp16 by pair id
  const int rbase = wrow + (lane >> 4) * 4;
#pragma unroll
  for (int m = 0; m < 2; ++m) {
#pragma unroll
    for (int n = 0; n < 4; ++n) {
      int cl = wcol + n * 16 + fr;
#pragma unroll
      for (int j = 0; j < 4; ++j) {
        int rl = rbase + m * 16 + j;
        int pr = row_pair[rl];
        if (pr >= 0) {
          float h1 = acc1[m][n][j], h2 = acc2[m][n][j];
          float sv = h1 / (1.f + __expf(-h1));
          act[(size_t)pr * FFN + (size_t)ct * BN + cl] = (_Float16)(sv * h2);
        }
      }
    }
  }
}

// Stage B: y = act @ fc2[e]^T, scale by routing weight, atomic-accumulate into out.
__global__ __launch_bounds__(512) void k_ffn2(const _Float16* __restrict__ act,
                                              const float* __restrict__ fc2,
                                              const int* __restrict__ lists,
                                              const int* __restrict__ cnt,
                                              const float* __restrict__ tokw,
                                              float* __restrict__ out) {
  const int e = blockIdx.z, rt = blockIdx.y, ct = blockIdx.x;
  const int count = cnt[e];
  if (rt * BM >= count) return;
  const int tid = threadIdx.x;

  __shared__ _Float16 As[2][BM][LDK];
  __shared__ _Float16 Bs[2][BN][LDK];
  __shared__ int row_pair[BM];
  __shared__ float row_w[BM];

  if (tid < BM) {
    int rg = rt * BM + tid;
    int pr = (rg < count) ? lists[e * TT + rg] : -1;
    row_pair[tid] = pr;
    row_w[tid] = (pr >= 0) ? tokw[pr] : 0.f;
  }
  __syncthreads();

  const int ra = tid >> 2, ca = (tid & 3) * 8;
  const int soffA = ra * LDK + ca;
  const _Float16* pa = (row_pair[ra] >= 0) ? (act + (size_t)row_pair[ra] * FFN + ca) : nullptr;
  const float* pb[2]; int soffB[2];
#pragma unroll
  for (int i = 0; i < 2; ++i) {
    int idx = tid + i * 512;
    int r = idx >> 3, c4 = (idx & 7) * 4;
    soffB[i] = r * LDK + c4;
    pb[i] = fc2 + ((size_t)e * HD + (size_t)ct * BN + r) * FFN + c4;
  }

  const f32x4 zero4 = {0.f, 0.f, 0.f, 0.f};
  const f16x8 zero8 = {0, 0, 0, 0, 0, 0, 0, 0};
  f16x8 la; f32x4 lb[2];
  auto load_tile = [&](int k0) {
    la = pa ? *(const f16x8*)(pa + k0) : zero8;
#pragma unroll
    for (int i = 0; i < 2; ++i) lb[i] = *(const f32x4*)(pb[i] + k0);
  };
  auto write_tile = [&](int buf) {
    *(f16x8*)&As[buf][0][soffA] = la;
#pragma unroll
    for (int i = 0; i < 2; ++i) *(f16x4*)&Bs[buf][0][soffB[i]] = cvt4(lb[i]);
  };

  f32x4 acc[2][4];
#pragma unroll
  for (int m = 0; m < 2; ++m)
#pragma unroll
    for (int n = 0; n < 4; ++n) acc[m][n] = zero4;

  const int lane = tid & 63;
  const int wv = tid >> 6;
  const int wrow = (wv >> 1) * 32;
  const int wcol = (wv & 1) * 64;
  const int fr = lane & 15;
  const int kg = lane >> 4;

  load_tile(0);
  write_tile(0);
  __syncthreads();

  const int NS = FFN / BK;  // 176
  for (int ks = 0; ks < NS; ++ks) {
    int buf = ks & 1;
    if (ks + 1 < NS) load_tile((ks + 1) * BK);
    f16x8 a[2], b[4];
#pragma unroll
    for (int m = 0; m < 2; ++m)
      a[m] = *(const f16x8*)&As[buf][wrow + m * 16 + fr][kg * 8];
#pragma unroll
    for (int n = 0; n < 4; ++n)
      b[n] = *(const f16x8*)&Bs[buf][wcol + n * 16 + fr][kg * 8];
#pragma unroll
    for (int m = 0; m < 2; ++m)
#pragma unroll
      for (int n = 0; n < 4; ++n)
        acc[m][n] = __builtin_amdgcn_mfma_f32_16x16x32_f16(a[m], b[n], acc[m][n], 0, 0, 0);
    if (ks + 1 < NS) write_tile(buf ^ 1);
    __syncthreads();
  }

  const int rbase = wrow + (lane >> 4) * 4;
#pragma unroll
  for (int m = 0; m < 2; ++m) {
#pragma unroll
    for (int n = 0; n < 4; ++n) {
      int cl = wcol + n * 16 + fr;
#pragma unroll
      for (int j = 0; j < 4; ++j) {
        int rl = rbase + m * 16 + j;
        int pr = row_pair[rl];
        if (pr >= 0) {
          float v = acc[m][n][j] * row_w[rl];
          unsafeAtomicAdd(out + (size_t)(pr >> 1) * HD + (size_t)ct * BN + cl, v);
        }
      }
    }
  }
}

extern "C" void kernel_launch(void* const* d_in, const int* in_sizes, int n_in,
                              void* d_out, int out_size, void* d_ws, size_t ws_size,
                              hipStream_t stream) {
  (void)in_sizes; (void)n_in; (void)out_size; (void)ws_size;
  const float* x    = (const float*)d_in[0];
  const float* wg   = (const float*)d_in[1];
  const float* wge  = (const float*)d_in[2];
  const float* fc11 = (const float*)d_in[3];
  const float* fc12 = (const float*)d_in[4];
  const float* fc2  = (const float*)d_in[5];
  float* out    = (float*)d_out;
  float* logits = out + (size_t)TT * HD;

  char* ws = (char*)d_ws;
  float* wr     = (float*)(ws + OFF_WR);
  int*   cnt    = (int*)(ws + OFF_CNT);
  int*   lists  = (int*)(ws + OFF_LISTS);
  float* tokw   = (float*)(ws + OFF_TOKW);
  _Float16* act = (_Float16*)(ws + OFF_ACT);

  hipMemsetAsync(out, 0, (size_t)TT * HD * sizeof(float), stream);
  hipMemsetAsync(cnt, 0, NE * sizeof(int), stream);

  k_prep<<<dim3((HD * NE + 255) / 256), 256, 0, stream>>>(wg, wge, wr);
  k_router<<<dim3(TT), 256, 0, stream>>>(x, wr, logits, tokw, lists, cnt);
  k_ffn1<<<dim3(FFN / BN, TT / BM, NE), 512, 0, stream>>>(x, fc11, fc12, lists, cnt, act);
  k_ffn2<<<dim3(HD / BN, TT / BM, NE), 512, 0, stream>>>(act, fc2, lists, cnt, tokw, out);
}